// Round 2
// baseline (533.479 us; speedup 1.0000x reference)
//
#include <hip/hip_runtime.h>
#include <cstdint>

typedef unsigned short u16;
typedef unsigned int   u32;

typedef __attribute__((ext_vector_type(8))) short bf16x8;
typedef __attribute__((ext_vector_type(4))) float f32x4;

#define DEV __device__ __forceinline__

static constexpr int HP = 66, WP = 66;   // padded spatial

DEV u16 f2bf(float f) {
  u32 u = __float_as_uint(f);
  u32 r = (u + 0x7fffu + ((u >> 16) & 1u)) >> 16;
  return (u16)r;
}
DEV float bf2f(u16 v) { return __uint_as_float((u32)v << 16); }

DEV void gload_lds16(const void* g, void* s) {
  __builtin_amdgcn_global_load_lds(
      (const __attribute__((address_space(1))) void*)g,
      (__attribute__((address_space(3))) void*)s, 16, 0, 0);
}

// ---------------- weight repack: OIHW fp32 -> [co][(ky*kdim+kx)*Cin+ci] bf16 ---------
__global__ __launch_bounds__(256) void repack_w_kernel(const float* __restrict__ src,
                                                       u16* __restrict__ dst,
                                                       int Cin, int K, int total,
                                                       int ksq, int kdim) {
  for (int idx = blockIdx.x * 256 + threadIdx.x; idx < total; idx += gridDim.x * 256) {
    int co = idx / K;
    int r  = idx - co * K;
    int s  = r / Cin;
    int ci = r - s * Cin;
    int ky = s / kdim, kx = s - ky * kdim;
    dst[idx] = f2bf(src[(co * Cin + ci) * ksq + ky * kdim + kx]);
  }
}

// ---------------- SS_T[i][o] = sum_{kh,kw} mod_w[o][i]^2 ----------------
__global__ __launch_bounds__(256) void modw_ss_kernel(const float* __restrict__ w,
                                                      float* __restrict__ SS_T) {
  int o = blockIdx.x, i = threadIdx.x;
  const float* p = w + (size_t)(o * 256 + i) * 9;
  float s = 0.f;
#pragma unroll
  for (int k = 0; k < 9; ++k) s += p[k] * p[k];
  SS_T[i * 256 + o] = s;
}

// ---------------- mvec[b][i] = style . style_w[i] + style_b[i] + 1 ----------------
__global__ __launch_bounds__(256) void style_mvec_kernel(const float* __restrict__ style,
                                                         const float* __restrict__ style_w,
                                                         const float* __restrict__ style_b,
                                                         float* __restrict__ mvec) {
  __shared__ float st[512];
  int b = blockIdx.x, t = threadIdx.x;
  for (int k = t; k < 512; k += 256) st[k] = style[b * 512 + k];
  __syncthreads();
  const float4* wr = (const float4*)(style_w + t * 512);
  float acc = 0.f;
  for (int k = 0; k < 128; ++k) {
    float4 w4 = wr[k];
    acc += w4.x * st[k*4] + w4.y * st[k*4+1] + w4.z * st[k*4+2] + w4.w * st[k*4+3];
  }
  mvec[b * 256 + t] = acc + style_b[t] + 1.f;
}

// ---------------- dvec[b][o] = rsqrt(sum_i mvec[b][i]^2 * SS_T[i][o] + eps) ---------
__global__ __launch_bounds__(256) void demod_kernel(const float* __restrict__ mvec,
                                                    const float* __restrict__ SS_T,
                                                    float* __restrict__ dvec) {
  __shared__ float m2[256];
  int b = blockIdx.x, t = threadIdx.x;
  float mv = mvec[b * 256 + t];
  m2[t] = mv * mv;
  __syncthreads();
  float acc = 0.f;
  for (int i = 0; i < 256; ++i) acc += m2[i] * SS_T[i * 256 + t];
  dvec[b * 256 + t] = rsqrtf(acc + 1e-8f);
}

// ---------------- tb2[b][co] = swish(temb[b]) . temb_w[co] + temb_b + conv1_b -------
__global__ __launch_bounds__(256) void temb_proj_kernel(const float* __restrict__ temb,
                                                        const float* __restrict__ temb_w,
                                                        const float* __restrict__ temb_b,
                                                        const float* __restrict__ conv1_b,
                                                        float* __restrict__ tb2) {
  __shared__ float sw[512];
  int b = blockIdx.x, t = threadIdx.x;
  for (int k = t; k < 512; k += 256) {
    float v = temb[b * 512 + k];
    sw[k] = v / (1.f + __expf(-v));
  }
  __syncthreads();
  const float4* wr = (const float4*)(temb_w + t * 512);
  float acc = 0.f;
  for (int k = 0; k < 128; ++k) {
    float4 w4 = wr[k];
    acc += w4.x * sw[k*4] + w4.y * sw[k*4+1] + w4.z * sw[k*4+2] + w4.w * sw[k*4+3];
  }
  tb2[b * 256 + t] = acc + temb_b[t] + conv1_b[t];
}

// ---------------- GN1 stats: per (b,g) over contiguous 16384 floats -----------------
__global__ __launch_bounds__(256) void gn1_stats_kernel(const float* __restrict__ x,
                                                        float2* __restrict__ st1) {
  int bg = blockIdx.x;
  const float4* p = (const float4*)(x + (size_t)bg * 16384);
  float s = 0.f, s2 = 0.f;
  for (int i = threadIdx.x; i < 4096; i += 256) {
    float4 v = p[i];
    s  += v.x + v.y + v.z + v.w;
    s2 += v.x*v.x + v.y*v.y + v.z*v.z + v.w*v.w;
  }
  for (int d = 32; d; d >>= 1) { s += __shfl_down(s, d); s2 += __shfl_down(s2, d); }
  __shared__ float red[2][4];
  if ((threadIdx.x & 63) == 0) { red[0][threadIdx.x >> 6] = s; red[1][threadIdx.x >> 6] = s2; }
  __syncthreads();
  if (threadIdx.x == 0) {
    s  = red[0][0] + red[0][1] + red[0][2] + red[0][3];
    s2 = red[1][0] + red[1][1] + red[1][2] + red[1][3];
    float mean = s / 16384.f;
    float var  = s2 / 16384.f - mean * mean;
    st1[bg] = make_float2(mean, rsqrtf(var + 1e-5f));
  }
}

// ---------------- GN1 apply + swish -> act1p (padded NHWC bf16); also x -> xh NHWC --
__global__ __launch_bounds__(256) void gn1_apply_kernel(const float* __restrict__ x,
                                                        const float2* __restrict__ st1,
                                                        const float* __restrict__ g1,
                                                        const float* __restrict__ b1,
                                                        u16* __restrict__ act1p,
                                                        u16* __restrict__ xh) {
  __shared__ float xs[128][65];
  int blk = blockIdx.x;
  int b = blk >> 6, y = blk & 63;
  int t = threadIdx.x;
#pragma unroll 8
  for (int pass = 0; pass < 32; ++pass) {
    int c = pass * 4 + (t >> 6);
    xs[c][t & 63] = x[(((size_t)b * 128 + c) * 64 + y) * 64 + (t & 63)];
  }
  __syncthreads();
  for (int pass = 0; pass < 32; ++pass) {
    int xc = pass * 2 + (t >> 7);
    int c  = t & 127;
    float v = xs[c][xc];
    float2 ms = st1[b * 32 + (c >> 2)];
    float vn = (v - ms.x) * ms.y * g1[c] + b1[c];
    float sw = vn / (1.f + __expf(-vn));
    act1p[(((size_t)b * HP + (y + 1)) * WP + (xc + 1)) * 128 + c] = f2bf(sw);
    xh[(((size_t)b * 64 + y) * 64 + xc) * 128 + c] = f2bf(v);
  }
}

// ---------------- GN2 partial sums (h1 NHWC bf16) ----------------
__global__ __launch_bounds__(256) void gn2_part_kernel(const u16* __restrict__ h1,
                                                       float2* __restrict__ part) {
  int b = blockIdx.x >> 4, chunk = blockIdx.x & 15;
  int t = threadIdx.x;
  int g = t & 31, sub = t >> 5;
  float s = 0.f, s2 = 0.f;
  const u16* base = h1 + ((size_t)b * 4096 + chunk * 256) * 256 + g * 8;
  for (int pp = 0; pp < 32; ++pp) {
    uint4 raw = *(const uint4*)(base + (size_t)(pp * 8 + sub) * 256);
    const u16* rs = (const u16*)&raw;
#pragma unroll
    for (int e = 0; e < 8; ++e) { float v = bf2f(rs[e]); s += v; s2 += v * v; }
  }
  s += __shfl_xor(s, 32); s2 += __shfl_xor(s2, 32);
  __shared__ float red[2][4][32];
  int wv = t >> 6, ln = t & 63;
  if (ln < 32) { red[0][wv][ln] = s; red[1][wv][ln] = s2; }
  __syncthreads();
  if (t < 32) {
    float ts  = red[0][0][t] + red[0][1][t] + red[0][2][t] + red[0][3][t];
    float ts2 = red[1][0][t] + red[1][1][t] + red[1][2][t] + red[1][3][t];
    part[(b * 16 + chunk) * 32 + t] = make_float2(ts, ts2);
  }
}

__global__ void gn2_final_kernel(const float2* __restrict__ part, float2* __restrict__ st2) {
  int idx = blockIdx.x * 256 + threadIdx.x;
  if (idx >= 1024) return;
  int b = idx >> 5, g = idx & 31;
  float s = 0.f, s2 = 0.f;
  for (int c = 0; c < 16; ++c) { float2 p = part[(b * 16 + c) * 32 + g]; s += p.x; s2 += p.y; }
  float mean = s / 32768.f;
  float var  = s2 / 32768.f - mean * mean;
  st2[idx] = make_float2(mean, rsqrtf(var + 1e-5f));
}

// ------- GN2 apply + swish + input-channel modulation: h1 -> act2p (padded NHWC) ----
__global__ __launch_bounds__(256) void gn2_apply_kernel(const u16* __restrict__ h1,
                                                        const float2* __restrict__ st2,
                                                        const float* __restrict__ g2,
                                                        const float* __restrict__ b2,
                                                        const float* __restrict__ mvec,
                                                        u16* __restrict__ act2p) {
  int idx = blockIdx.x * 256 + threadIdx.x;  // granule id
  int gpix = idx >> 5;
  int gi = idx & 31;
  int c0 = gi * 8;
  int b = gpix >> 12, y = (gpix >> 6) & 63, x = gpix & 63;
  uint4 raw = *(const uint4*)(h1 + (size_t)gpix * 256 + c0);
  const u16* rs = (const u16*)&raw;
  float2 ms = st2[b * 32 + gi];
  const float* mv = mvec + b * 256 + c0;
  u16 outp[8];
#pragma unroll
  for (int e = 0; e < 8; ++e) {
    float v  = bf2f(rs[e]);
    float vn = (v - ms.x) * ms.y * g2[c0 + e] + b2[c0 + e];
    float sw = vn / (1.f + __expf(-vn));
    outp[e] = f2bf(sw * mv[e]);
  }
  *(uint4*)(act2p + (((size_t)b * HP + (y + 1)) * WP + (x + 1)) * 256 + c0) = *(const uint4*)outp;
}

// ---------------- implicit-GEMM conv: 128x128 tile, BK=64, mfma 16x16x32 bf16 -------
// MODE 0: conv1  -> h1 bf16 NHWC, epi = tb2[b*256+co] (includes conv1_b)
// MODE 1: sc 1x1 -> d_out NCHW fp32 (=v+sc_b), epi = sc_b
// MODE 2: modconv-> d_out NCHW fp32 (+= v*dvec), epi = dvec[b*256+co]
template <int MODE>
__global__ __launch_bounds__(256) void igemm_kernel(const u16* __restrict__ act,
                                                    const u16* __restrict__ wT,
                                                    const float* __restrict__ epi,
                                                    u16* __restrict__ h1out,
                                                    float* __restrict__ fout,
                                                    int K, int Cin, int Hp, int Wp, int KHW) {
  __shared__ __align__(16) unsigned char lds[33536];
  const int tid  = threadIdx.x;
  const int wave = tid >> 6, lane = tid & 63;
  const int wm = wave >> 1, wn = wave & 1;
  const int mtile = blockIdx.x, ntile = blockIdx.y;
  const int m_base = mtile * 128;
  const int bimg = m_base >> 12;

  // staging constants: linear granule q = j*256+tid; row=q>>3; phys granule=q&7
  const int grow  = tid >> 3;          // row within 32-row j-chunk
  const int gphys = tid & 7;
  const int glog  = gphys ^ (grow & 7);  // inverse-swizzled source granule

  size_t pixbase[4];
  int    nrowbase[4];
#pragma unroll
  for (int j = 0; j < 4; ++j) {
    int row = j * 32 + grow;
    int m = m_base + row;
    int b = m >> 12, y = (m >> 6) & 63, x = m & 63;
    pixbase[j]  = ((size_t)(b * Hp + y) * Wp + x) * Cin + glog * 8;
    nrowbase[j] = (ntile * 128 + row) * K + glog * 8;
  }

  f32x4 acc[4][4];
#pragma unroll
  for (int i = 0; i < 4; ++i)
#pragma unroll
    for (int j = 0; j < 4; ++j) acc[i][j] = (f32x4){0.f, 0.f, 0.f, 0.f};

  unsigned char* As = lds;
  unsigned char* Bs = lds + 16384;

  int kt = 0;
  for (int ky = 0; ky < KHW; ++ky)
    for (int kx = 0; kx < KHW; ++kx)
      for (int kin = 0; kin < Cin; kin += 64, ++kt) {
        const int koffA = (ky * Wp + kx) * Cin + kin;
        const int k0 = kt * 64;
        __syncthreads();
#pragma unroll
        for (int j = 0; j < 4; ++j) {
          gload_lds16(act + pixbase[j] + koffA, As + j * 4096 + wave * 1024);
          gload_lds16(wT + nrowbase[j] + k0,    Bs + j * 4096 + wave * 1024);
        }
        __syncthreads();
#pragma unroll
        for (int kk = 0; kk < 2; ++kk) {
          bf16x8 afr[4], bfr[4];
#pragma unroll
          for (int f = 0; f < 4; ++f) {
            int rowA = wm * 64 + f * 16 + (lane & 15);
            int gA = (kk * 4 + (lane >> 4)) ^ (rowA & 7);
            afr[f] = *(const bf16x8*)(As + rowA * 128 + gA * 16);
            int rowB = wn * 64 + f * 16 + (lane & 15);
            int gB = (kk * 4 + (lane >> 4)) ^ (rowB & 7);
            bfr[f] = *(const bf16x8*)(Bs + rowB * 128 + gB * 16);
          }
#pragma unroll
          for (int fm = 0; fm < 4; ++fm)
#pragma unroll
            for (int fn = 0; fn < 4; ++fn)
              acc[fm][fn] = __builtin_amdgcn_mfma_f32_16x16x32_bf16(afr[fm], bfr[fn],
                                                                    acc[fm][fn], 0, 0, 0);
        }
      }

  if (MODE == 0) {
    const int r0 = m_base + wm * 64 + ((lane >> 4) << 2);
    const int c0 = ntile * 128 + wn * 64 + (lane & 15);
    const float* tbrow = epi + bimg * 256;
#pragma unroll
    for (int fm = 0; fm < 4; ++fm)
#pragma unroll
      for (int fn = 0; fn < 4; ++fn) {
        int co = c0 + fn * 16;
        float add = tbrow[co];
#pragma unroll
        for (int i = 0; i < 4; ++i) {
          int m = r0 + fm * 16 + i;
          h1out[(size_t)m * 256 + co] = f2bf(acc[fm][fn][i] + add);
        }
      }
  } else {
    float* tile = (float*)lds;  // [64][130]
    const int y0 = (m_base >> 6) & 63;
#pragma unroll
    for (int half = 0; half < 2; ++half) {
      __syncthreads();
      if (wn == half) {
#pragma unroll
        for (int fn = 0; fn < 4; ++fn) {
          int nl = fn * 16 + (lane & 15);
          int co = ntile * 128 + half * 64 + nl;
          float sc = (MODE == 2) ? epi[bimg * 256 + co] : 0.f;
#pragma unroll
          for (int fm = 0; fm < 4; ++fm)
#pragma unroll
            for (int i = 0; i < 4; ++i) {
              int ml = wm * 64 + fm * 16 + ((lane >> 4) << 2) + i;
              float v = acc[fm][fn][i];
              if (MODE == 2) v *= sc;
              tile[nl * 130 + ml] = v;
            }
        }
      }
      __syncthreads();
      for (int it = 0; it < 32; ++it) {
        int col = it * 2 + (tid >> 7);
        int ml  = tid & 127;
        float v = tile[col * 130 + ml];
        int co = ntile * 128 + half * 64 + col;
        int y = y0 + (ml >> 6), x = ml & 63;
        size_t oidx = (((size_t)(bimg * 256 + co)) * 64 + y) * 64 + x;
        if (MODE == 1) fout[oidx] = v + epi[co];
        else           fout[oidx] += v;
      }
    }
  }
}

// ------------------------------- launch -------------------------------
extern "C" void kernel_launch(void* const* d_in, const int* in_sizes, int n_in,
                              void* d_out, int out_size, void* d_ws, size_t ws_size,
                              hipStream_t stream) {
  const float* x       = (const float*)d_in[0];
  const float* temb    = (const float*)d_in[1];
  const float* style   = (const float*)d_in[2];
  const float* gn1_g   = (const float*)d_in[3];
  const float* gn1_b   = (const float*)d_in[4];
  const float* conv1_w = (const float*)d_in[5];
  const float* conv1_b = (const float*)d_in[6];
  const float* temb_w  = (const float*)d_in[7];
  const float* temb_b  = (const float*)d_in[8];
  const float* gn2_g   = (const float*)d_in[9];
  const float* gn2_b   = (const float*)d_in[10];
  const float* style_w = (const float*)d_in[11];
  const float* style_b = (const float*)d_in[12];
  const float* mod_w   = (const float*)d_in[13];
  const float* sc_w    = (const float*)d_in[14];
  const float* sc_b    = (const float*)d_in[15];
  float* out = (float*)d_out;
  char* ws = (char*)d_ws;

  size_t o = 0;
  auto alloc = [&](size_t bytes) { size_t r = o; o += (bytes + 255) & ~(size_t)255; return r; };
  const size_t act1p_bytes = (size_t)32 * HP * WP * 128 * 2;  // 35,684,352
  const size_t xh_bytes    = (size_t)32 * 64 * 64 * 128 * 2;  // 33,554,432
  const size_t h1_bytes    = (size_t)32 * 4096 * 256 * 2;     // 67,108,864
  const size_t act2p_bytes = (size_t)32 * HP * WP * 256 * 2;  // 71,368,704
  size_t o_act1p = alloc(act1p_bytes);
  size_t o_xh    = alloc(xh_bytes);
  size_t o_h1    = alloc(h1_bytes);
  size_t o_act2p = alloc(act2p_bytes);
  size_t o_w1T   = alloc((size_t)256 * 1152 * 2);
  size_t o_wmT   = alloc((size_t)256 * 2304 * 2);
  size_t o_scT   = alloc((size_t)256 * 128 * 2);
  size_t o_tb2   = alloc(8192 * 4);
  size_t o_mvec  = alloc(8192 * 4);
  size_t o_dvec  = alloc(8192 * 4);
  size_t o_SS    = alloc((size_t)256 * 256 * 4);
  size_t o_st1   = alloc(1024 * 8);
  size_t o_st2   = alloc(1024 * 8);
  size_t o_part  = alloc(512 * 32 * 8);
  if (ws_size < o) return;  // workspace too small

  u16*    act1p = (u16*)(ws + o_act1p);
  u16*    xh    = (u16*)(ws + o_xh);
  u16*    h1    = (u16*)(ws + o_h1);
  u16*    act2p = (u16*)(ws + o_act2p);
  u16*    w1T   = (u16*)(ws + o_w1T);
  u16*    wmT   = (u16*)(ws + o_wmT);
  u16*    scT   = (u16*)(ws + o_scT);
  float*  tb2   = (float*)(ws + o_tb2);
  float*  mvec  = (float*)(ws + o_mvec);
  float*  dvec  = (float*)(ws + o_dvec);
  float*  SS_T  = (float*)(ws + o_SS);
  float2* st1   = (float2*)(ws + o_st1);
  float2* st2   = (float2*)(ws + o_st2);
  float2* part  = (float2*)(ws + o_part);

  // zero halos (interiors are fully overwritten)
  hipMemsetAsync(act1p, 0, act1p_bytes, stream);
  hipMemsetAsync(act2p, 0, act2p_bytes, stream);

  repack_w_kernel<<<1152, 256, 0, stream>>>(conv1_w, w1T, 128, 1152, 256 * 1152, 9, 3);
  repack_w_kernel<<<2304, 256, 0, stream>>>(mod_w, wmT, 256, 2304, 256 * 2304, 9, 3);
  repack_w_kernel<<<128, 256, 0, stream>>>(sc_w, scT, 128, 128, 256 * 128, 1, 1);
  modw_ss_kernel<<<256, 256, 0, stream>>>(mod_w, SS_T);
  temb_proj_kernel<<<32, 256, 0, stream>>>(temb, temb_w, temb_b, conv1_b, tb2);
  style_mvec_kernel<<<32, 256, 0, stream>>>(style, style_w, style_b, mvec);
  demod_kernel<<<32, 256, 0, stream>>>(mvec, SS_T, dvec);
  gn1_stats_kernel<<<1024, 256, 0, stream>>>(x, st1);
  gn1_apply_kernel<<<2048, 256, 0, stream>>>(x, st1, gn1_g, gn1_b, act1p, xh);

  igemm_kernel<0><<<dim3(1024, 2), 256, 0, stream>>>(act1p, w1T, tb2, h1, nullptr,
                                                     1152, 128, HP, WP, 3);

  gn2_part_kernel<<<512, 256, 0, stream>>>(h1, part);
  gn2_final_kernel<<<4, 256, 0, stream>>>(part, st2);
  gn2_apply_kernel<<<16384, 256, 0, stream>>>(h1, st2, gn2_g, gn2_b, mvec, act2p);

  igemm_kernel<1><<<dim3(1024, 2), 256, 0, stream>>>(xh, scT, sc_b, nullptr, out,
                                                     128, 128, 64, 64, 1);
  igemm_kernel<2><<<dim3(1024, 2), 256, 0, stream>>>(act2p, wmT, dvec, nullptr, out,
                                                     2304, 256, HP, WP, 3);
}

// Round 3
// 504.285 us; speedup vs baseline: 1.0579x; 1.0579x over previous
//
#include <hip/hip_runtime.h>
#include <cstdint>

typedef unsigned short u16;
typedef unsigned int   u32;

typedef __attribute__((ext_vector_type(8))) short bf16x8;
typedef __attribute__((ext_vector_type(4))) float f32x4;

#define DEV __device__ __forceinline__

static constexpr int HP = 66, WP = 66;   // padded spatial

DEV u16 f2bf(float f) {
  u32 u = __float_as_uint(f);
  u32 r = (u + 0x7fffu + ((u >> 16) & 1u)) >> 16;
  return (u16)r;
}
DEV float bf2f(u16 v) { return __uint_as_float((u32)v << 16); }

DEV void gload_lds16(const void* g, void* s) {
  __builtin_amdgcn_global_load_lds(
      (const __attribute__((address_space(1))) void*)g,
      (__attribute__((address_space(3))) void*)s, 16, 0, 0);
}

// ---------------- weight repack: OIHW fp32 -> [co][(ky*kdim+kx)*Cin+ci] bf16 ---------
__global__ __launch_bounds__(256) void repack_w_kernel(const float* __restrict__ src,
                                                       u16* __restrict__ dst,
                                                       int Cin, int K, int total,
                                                       int ksq, int kdim) {
  for (int idx = blockIdx.x * 256 + threadIdx.x; idx < total; idx += gridDim.x * 256) {
    int co = idx / K;
    int r  = idx - co * K;
    int s  = r / Cin;
    int ci = r - s * Cin;
    int ky = s / kdim, kx = s - ky * kdim;
    dst[idx] = f2bf(src[(co * Cin + ci) * ksq + ky * kdim + kx]);
  }
}

// ---------------- SS_T[i][o] = sum_{kh,kw} mod_w[o][i]^2 ----------------
__global__ __launch_bounds__(256) void modw_ss_kernel(const float* __restrict__ w,
                                                      float* __restrict__ SS_T) {
  int o = blockIdx.x, i = threadIdx.x;
  const float* p = w + (size_t)(o * 256 + i) * 9;
  float s = 0.f;
#pragma unroll
  for (int k = 0; k < 9; ++k) s += p[k] * p[k];
  SS_T[i * 256 + o] = s;
}

// ---------------- mvec[b][i] = style . style_w[i] + style_b[i] + 1 ----------------
__global__ __launch_bounds__(256) void style_mvec_kernel(const float* __restrict__ style,
                                                         const float* __restrict__ style_w,
                                                         const float* __restrict__ style_b,
                                                         float* __restrict__ mvec) {
  __shared__ float st[512];
  int b = blockIdx.x, t = threadIdx.x;
  for (int k = t; k < 512; k += 256) st[k] = style[b * 512 + k];
  __syncthreads();
  const float4* wr = (const float4*)(style_w + t * 512);
  float acc = 0.f;
  for (int k = 0; k < 128; ++k) {
    float4 w4 = wr[k];
    acc += w4.x * st[k*4] + w4.y * st[k*4+1] + w4.z * st[k*4+2] + w4.w * st[k*4+3];
  }
  mvec[b * 256 + t] = acc + style_b[t] + 1.f;
}

// ---------------- dvec[b][o] = rsqrt(sum_i mvec[b][i]^2 * SS_T[i][o] + eps) ---------
__global__ __launch_bounds__(256) void demod_kernel(const float* __restrict__ mvec,
                                                    const float* __restrict__ SS_T,
                                                    float* __restrict__ dvec) {
  __shared__ float m2[256];
  int b = blockIdx.x, t = threadIdx.x;
  float mv = mvec[b * 256 + t];
  m2[t] = mv * mv;
  __syncthreads();
  float acc = 0.f;
  for (int i = 0; i < 256; ++i) acc += m2[i] * SS_T[i * 256 + t];
  dvec[b * 256 + t] = rsqrtf(acc + 1e-8f);
}

// ---------------- tb2[b][co] = swish(temb[b]) . temb_w[co] + temb_b + conv1_b -------
__global__ __launch_bounds__(256) void temb_proj_kernel(const float* __restrict__ temb,
                                                        const float* __restrict__ temb_w,
                                                        const float* __restrict__ temb_b,
                                                        const float* __restrict__ conv1_b,
                                                        float* __restrict__ tb2) {
  __shared__ float sw[512];
  int b = blockIdx.x, t = threadIdx.x;
  for (int k = t; k < 512; k += 256) {
    float v = temb[b * 512 + k];
    sw[k] = v / (1.f + __expf(-v));
  }
  __syncthreads();
  const float4* wr = (const float4*)(temb_w + t * 512);
  float acc = 0.f;
  for (int k = 0; k < 128; ++k) {
    float4 w4 = wr[k];
    acc += w4.x * sw[k*4] + w4.y * sw[k*4+1] + w4.z * sw[k*4+2] + w4.w * sw[k*4+3];
  }
  tb2[b * 256 + t] = acc + temb_b[t] + conv1_b[t];
}

// ---------------- halo zero: clear only border pixels of padded NHWC buffer ---------
template <int C>
__global__ __launch_bounds__(256) void halo_zero_kernel(u16* __restrict__ buf) {
  int idx = blockIdx.x * 256 + threadIdx.x;
  const int GR = C / 8;
  if (idx >= 32 * 260 * GR) return;
  int g = idx % GR;
  int p = (idx / GR) % 260;
  int b = idx / (GR * 260);
  int y, x;
  if (p < 66)       { y = 0;        x = p; }
  else if (p < 132) { y = 65;       x = p - 66; }
  else if (p < 196) { y = p - 131;  x = 0; }
  else              { y = p - 195;  x = 65; }
  uint4 z; z.x = 0; z.y = 0; z.z = 0; z.w = 0;
  *(uint4*)(buf + (((size_t)b * HP + y) * WP + x) * C + g * 8) = z;
}

// ---------------- GN1 stats: per (b,g) over contiguous 16384 floats -----------------
__global__ __launch_bounds__(256) void gn1_stats_kernel(const float* __restrict__ x,
                                                        float2* __restrict__ st1) {
  int bg = blockIdx.x;
  const float4* p = (const float4*)(x + (size_t)bg * 16384);
  float s = 0.f, s2 = 0.f;
  for (int i = threadIdx.x; i < 4096; i += 256) {
    float4 v = p[i];
    s  += v.x + v.y + v.z + v.w;
    s2 += v.x*v.x + v.y*v.y + v.z*v.z + v.w*v.w;
  }
  for (int d = 32; d; d >>= 1) { s += __shfl_down(s, d); s2 += __shfl_down(s2, d); }
  __shared__ float red[2][4];
  if ((threadIdx.x & 63) == 0) { red[0][threadIdx.x >> 6] = s; red[1][threadIdx.x >> 6] = s2; }
  __syncthreads();
  if (threadIdx.x == 0) {
    s  = red[0][0] + red[0][1] + red[0][2] + red[0][3];
    s2 = red[1][0] + red[1][1] + red[1][2] + red[1][3];
    float mean = s / 16384.f;
    float var  = s2 / 16384.f - mean * mean;
    st1[bg] = make_float2(mean, rsqrtf(var + 1e-5f));
  }
}

// ---------------- GN1 apply + swish -> act1p (padded NHWC bf16); also x -> xh NHWC --
__global__ __launch_bounds__(256) void gn1_apply_kernel(const float* __restrict__ x,
                                                        const float2* __restrict__ st1,
                                                        const float* __restrict__ g1,
                                                        const float* __restrict__ b1,
                                                        u16* __restrict__ act1p,
                                                        u16* __restrict__ xh) {
  __shared__ float xs[128][65];
  int blk = blockIdx.x;
  int b = blk >> 6, y = blk & 63;
  int t = threadIdx.x;
#pragma unroll 8
  for (int pass = 0; pass < 32; ++pass) {
    int c = pass * 4 + (t >> 6);
    xs[c][t & 63] = x[(((size_t)b * 128 + c) * 64 + y) * 64 + (t & 63)];
  }
  __syncthreads();
  for (int pass = 0; pass < 32; ++pass) {
    int xc = pass * 2 + (t >> 7);
    int c  = t & 127;
    float v = xs[c][xc];
    float2 ms = st1[b * 32 + (c >> 2)];
    float vn = (v - ms.x) * ms.y * g1[c] + b1[c];
    float sw = vn / (1.f + __expf(-vn));
    act1p[(((size_t)b * HP + (y + 1)) * WP + (xc + 1)) * 128 + c] = f2bf(sw);
    xh[(((size_t)b * 64 + y) * 64 + xc) * 128 + c] = f2bf(v);
  }
}

// ---------------- GN2 partial sums (h1 NHWC bf16) ----------------
__global__ __launch_bounds__(256) void gn2_part_kernel(const u16* __restrict__ h1,
                                                       float2* __restrict__ part) {
  int b = blockIdx.x >> 4, chunk = blockIdx.x & 15;
  int t = threadIdx.x;
  int g = t & 31, sub = t >> 5;
  float s = 0.f, s2 = 0.f;
  const u16* base = h1 + ((size_t)b * 4096 + chunk * 256) * 256 + g * 8;
  for (int pp = 0; pp < 32; ++pp) {
    uint4 raw = *(const uint4*)(base + (size_t)(pp * 8 + sub) * 256);
    const u16* rs = (const u16*)&raw;
#pragma unroll
    for (int e = 0; e < 8; ++e) { float v = bf2f(rs[e]); s += v; s2 += v * v; }
  }
  s += __shfl_xor(s, 32); s2 += __shfl_xor(s2, 32);
  __shared__ float red[2][4][32];
  int wv = t >> 6, ln = t & 63;
  if (ln < 32) { red[0][wv][ln] = s; red[1][wv][ln] = s2; }
  __syncthreads();
  if (t < 32) {
    float ts  = red[0][0][t] + red[0][1][t] + red[0][2][t] + red[0][3][t];
    float ts2 = red[1][0][t] + red[1][1][t] + red[1][2][t] + red[1][3][t];
    part[(b * 16 + chunk) * 32 + t] = make_float2(ts, ts2);
  }
}

__global__ void gn2_final_kernel(const float2* __restrict__ part, float2* __restrict__ st2) {
  int idx = blockIdx.x * 256 + threadIdx.x;
  if (idx >= 1024) return;
  int b = idx >> 5, g = idx & 31;
  float s = 0.f, s2 = 0.f;
  for (int c = 0; c < 16; ++c) { float2 p = part[(b * 16 + c) * 32 + g]; s += p.x; s2 += p.y; }
  float mean = s / 32768.f;
  float var  = s2 / 32768.f - mean * mean;
  st2[idx] = make_float2(mean, rsqrtf(var + 1e-5f));
}

// ------- GN2 apply + swish + input-channel modulation: h1 -> act2p (padded NHWC) ----
__global__ __launch_bounds__(256) void gn2_apply_kernel(const u16* __restrict__ h1,
                                                        const float2* __restrict__ st2,
                                                        const float* __restrict__ g2,
                                                        const float* __restrict__ b2,
                                                        const float* __restrict__ mvec,
                                                        u16* __restrict__ act2p) {
  int idx = blockIdx.x * 256 + threadIdx.x;  // granule id
  int gpix = idx >> 5;
  int gi = idx & 31;
  int c0 = gi * 8;
  int b = gpix >> 12, y = (gpix >> 6) & 63, x = gpix & 63;
  uint4 raw = *(const uint4*)(h1 + (size_t)gpix * 256 + c0);
  const u16* rs = (const u16*)&raw;
  float2 ms = st2[b * 32 + gi];
  const float* mv = mvec + b * 256 + c0;
  u16 outp[8];
#pragma unroll
  for (int e = 0; e < 8; ++e) {
    float v  = bf2f(rs[e]);
    float vn = (v - ms.x) * ms.y * g2[c0 + e] + b2[c0 + e];
    float sw = vn / (1.f + __expf(-vn));
    outp[e] = f2bf(sw * mv[e]);
  }
  *(uint4*)(act2p + (((size_t)b * HP + (y + 1)) * WP + (x + 1)) * 256 + c0) = *(const uint4*)outp;
}

// ------------- implicit-GEMM conv: 128x128 tile, BK=64, double-buffered -------------
// MODE 0: conv1  (Cin=128, 3x3) -> h1 bf16 NHWC, epi = tb2 (incl conv1_b)
// MODE 2: modconv(Cin=256, 3x3) + fused 1x1 shortcut over xh/scT
//         -> d_out NCHW fp32 = accM*dvec + accS + sc_b
template <int MODE>
__global__ __launch_bounds__(256) void igemm_kernel(const u16* __restrict__ act,
                                                    const u16* __restrict__ wT,
                                                    const float* __restrict__ epi,
                                                    const u16* __restrict__ xh,
                                                    const u16* __restrict__ scT,
                                                    const float* __restrict__ sc_b,
                                                    u16* __restrict__ h1out,
                                                    float* __restrict__ fout) {
  constexpr int CIN    = (MODE == 0) ? 128 : 256;
  constexpr int NSUB   = CIN / 64;          // K-substeps per tap
  constexpr int KW     = CIN * 9;           // weight K (main)
  constexpr int NKMAIN = KW / 64;           // 18 / 36
  constexpr int NKT    = (MODE == 2) ? NKMAIN + 2 : NKMAIN;

  __shared__ __align__(16) unsigned char lds[65536];
  const int tid  = threadIdx.x;
  const int wave = tid >> 6, lane = tid & 63;
  const int wm = wave >> 1, wn = wave & 1;
  const int mtile = blockIdx.x, ntile = blockIdx.y;
  const int m_base = mtile * 128;
  const int bimg = m_base >> 12;

  // staging: linear granule; row = within-chunk row, phys granule = tid&7
  const int grow  = tid >> 3;
  const int gphys = tid & 7;
  const int glog  = gphys ^ (grow & 7);   // pre-swizzled source granule

  u32 pixbaseM[4], pixbaseX[4], nrowbaseM[4], nrowbaseS[4];
#pragma unroll
  for (int j = 0; j < 4; ++j) {
    int row = j * 32 + grow;
    int m = m_base + row;
    int b = m >> 12, y = (m >> 6) & 63, x = m & 63;
    pixbaseM[j]  = (u32)((b * HP + y) * WP + x) * CIN + glog * 8;
    nrowbaseM[j] = (u32)(ntile * 128 + row) * KW + glog * 8;
    if (MODE == 2) {
      pixbaseX[j]  = (u32)((b * 64 + y) * 64 + x) * 128 + glog * 8;
      nrowbaseS[j] = (u32)(ntile * 128 + row) * 128 + glog * 8;
    }
  }

  f32x4 accM[4][4], accS[4][4];
#pragma unroll
  for (int i = 0; i < 4; ++i)
#pragma unroll
    for (int j = 0; j < 4; ++j) { accM[i][j] = (f32x4){0,0,0,0}; accS[i][j] = (f32x4){0,0,0,0}; }

  auto stage = [&](int kt, int buf) {
    unsigned char* As = lds + buf * 32768;
    unsigned char* Bs = As + 16384;
    if (MODE == 2 && kt >= NKMAIN) {
      u32 koff = (u32)(kt - NKMAIN) * 64;
#pragma unroll
      for (int j = 0; j < 4; ++j) {
        gload_lds16(xh  + pixbaseX[j]  + koff, As + j * 4096 + wave * 1024);
        gload_lds16(scT + nrowbaseS[j] + koff, Bs + j * 4096 + wave * 1024);
      }
    } else {
      int tap = kt / NSUB;
      int kin = (kt % NSUB) * 64;
      int ky = tap / 3, kx = tap - ky * 3;
      u32 koffA = (u32)((ky * WP + kx) * CIN + kin);
      u32 koffB = (u32)kt * 64;
#pragma unroll
      for (int j = 0; j < 4; ++j) {
        gload_lds16(act + pixbaseM[j] + koffA, As + j * 4096 + wave * 1024);
        gload_lds16(wT  + nrowbaseM[j] + koffB, Bs + j * 4096 + wave * 1024);
      }
    }
  };

  auto compute = [&](int buf, f32x4 (&ac)[4][4]) {
    unsigned char* As = lds + buf * 32768;
    unsigned char* Bs = As + 16384;
#pragma unroll
    for (int kk = 0; kk < 2; ++kk) {
      bf16x8 afr[4], bfr[4];
#pragma unroll
      for (int f = 0; f < 4; ++f) {
        int rowA = wm * 64 + f * 16 + (lane & 15);
        int gA = (kk * 4 + (lane >> 4)) ^ (rowA & 7);
        afr[f] = *(const bf16x8*)(As + rowA * 128 + gA * 16);
        int rowB = wn * 64 + f * 16 + (lane & 15);
        int gB = (kk * 4 + (lane >> 4)) ^ (rowB & 7);
        bfr[f] = *(const bf16x8*)(Bs + rowB * 128 + gB * 16);
      }
#pragma unroll
      for (int fm = 0; fm < 4; ++fm)
#pragma unroll
        for (int fn = 0; fn < 4; ++fn)
          ac[fm][fn] = __builtin_amdgcn_mfma_f32_16x16x32_bf16(afr[fm], bfr[fn],
                                                               ac[fm][fn], 0, 0, 0);
    }
  };

  // ---- 2-phase pipelined K-loop: stage(kt+1) overlaps compute(kt) ----
  stage(0, 0);
#pragma unroll 2
  for (int kt = 0; kt < NKT; ++kt) {
    const int cur = kt & 1;
    if (kt + 1 < NKT) {
      stage(kt + 1, cur ^ 1);
      asm volatile("s_waitcnt vmcnt(8)" ::: "memory");   // wait only kt's 8 loads
    } else {
      asm volatile("s_waitcnt vmcnt(0)" ::: "memory");   // last tile: drain
    }
    __builtin_amdgcn_s_barrier();            // buf[cur] ready for all waves
    __builtin_amdgcn_sched_barrier(0);       // pin ds_reads below the barrier
    if (MODE == 2 && kt >= NKMAIN) compute(cur, accS);
    else                           compute(cur, accM);
    asm volatile("s_waitcnt lgkmcnt(0)" ::: "memory");   // my reads of buf[cur] done
    __builtin_amdgcn_s_barrier();            // release buf[cur] for restaging
  }

  if (MODE == 0) {
    const int r0 = m_base + wm * 64 + ((lane >> 4) << 2);
    const int c0 = ntile * 128 + wn * 64 + (lane & 15);
    const float* tbrow = epi + bimg * 256;
#pragma unroll
    for (int fm = 0; fm < 4; ++fm)
#pragma unroll
      for (int fn = 0; fn < 4; ++fn) {
        int co = c0 + fn * 16;
        float add = tbrow[co];
#pragma unroll
        for (int i = 0; i < 4; ++i) {
          int m = r0 + fm * 16 + i;
          h1out[(size_t)m * 256 + co] = f2bf(accM[fm][fn][i] + add);
        }
      }
  } else {
    float* tile = (float*)lds;  // [64][130]
    const int y0 = (m_base >> 6) & 63;
#pragma unroll
    for (int half = 0; half < 2; ++half) {
      __syncthreads();
      if (wn == half) {
#pragma unroll
        for (int fn = 0; fn < 4; ++fn) {
          int nl = fn * 16 + (lane & 15);
          int co = ntile * 128 + half * 64 + nl;
          float dsc = epi[bimg * 256 + co];
          float scb = sc_b[co];
#pragma unroll
          for (int fm = 0; fm < 4; ++fm)
#pragma unroll
            for (int i = 0; i < 4; ++i) {
              int ml = wm * 64 + fm * 16 + ((lane >> 4) << 2) + i;
              tile[nl * 130 + ml] = accM[fm][fn][i] * dsc + accS[fm][fn][i] + scb;
            }
        }
      }
      __syncthreads();
      for (int it = 0; it < 32; ++it) {
        int col = it * 2 + (tid >> 7);
        int ml  = tid & 127;
        float v = tile[col * 130 + ml];
        int co = ntile * 128 + half * 64 + col;
        int y = y0 + (ml >> 6), x = ml & 63;
        size_t oidx = (((size_t)(bimg * 256 + co)) * 64 + y) * 64 + x;
        fout[oidx] = v;
      }
    }
  }
}

// ------------------------------- launch -------------------------------
extern "C" void kernel_launch(void* const* d_in, const int* in_sizes, int n_in,
                              void* d_out, int out_size, void* d_ws, size_t ws_size,
                              hipStream_t stream) {
  const float* x       = (const float*)d_in[0];
  const float* temb    = (const float*)d_in[1];
  const float* style   = (const float*)d_in[2];
  const float* gn1_g   = (const float*)d_in[3];
  const float* gn1_b   = (const float*)d_in[4];
  const float* conv1_w = (const float*)d_in[5];
  const float* conv1_b = (const float*)d_in[6];
  const float* temb_w  = (const float*)d_in[7];
  const float* temb_b  = (const float*)d_in[8];
  const float* gn2_g   = (const float*)d_in[9];
  const float* gn2_b   = (const float*)d_in[10];
  const float* style_w = (const float*)d_in[11];
  const float* style_b = (const float*)d_in[12];
  const float* mod_w   = (const float*)d_in[13];
  const float* sc_w    = (const float*)d_in[14];
  const float* sc_b    = (const float*)d_in[15];
  float* out = (float*)d_out;
  char* ws = (char*)d_ws;

  size_t o = 0;
  auto alloc = [&](size_t bytes) { size_t r = o; o += (bytes + 255) & ~(size_t)255; return r; };
  const size_t act1p_bytes = (size_t)32 * HP * WP * 128 * 2;
  const size_t xh_bytes    = (size_t)32 * 64 * 64 * 128 * 2;
  const size_t h1_bytes    = (size_t)32 * 4096 * 256 * 2;
  const size_t act2p_bytes = (size_t)32 * HP * WP * 256 * 2;
  size_t o_act1p = alloc(act1p_bytes);
  size_t o_xh    = alloc(xh_bytes);
  size_t o_h1    = alloc(h1_bytes);
  size_t o_act2p = alloc(act2p_bytes);
  size_t o_w1T   = alloc((size_t)256 * 1152 * 2);
  size_t o_wmT   = alloc((size_t)256 * 2304 * 2);
  size_t o_scT   = alloc((size_t)256 * 128 * 2);
  size_t o_tb2   = alloc(8192 * 4);
  size_t o_mvec  = alloc(8192 * 4);
  size_t o_dvec  = alloc(8192 * 4);
  size_t o_SS    = alloc((size_t)256 * 256 * 4);
  size_t o_st1   = alloc(1024 * 8);
  size_t o_st2   = alloc(1024 * 8);
  size_t o_part  = alloc(512 * 32 * 8);
  if (ws_size < o) return;

  u16*    act1p = (u16*)(ws + o_act1p);
  u16*    xh    = (u16*)(ws + o_xh);
  u16*    h1    = (u16*)(ws + o_h1);
  u16*    act2p = (u16*)(ws + o_act2p);
  u16*    w1T   = (u16*)(ws + o_w1T);
  u16*    wmT   = (u16*)(ws + o_wmT);
  u16*    scT   = (u16*)(ws + o_scT);
  float*  tb2   = (float*)(ws + o_tb2);
  float*  mvec  = (float*)(ws + o_mvec);
  float*  dvec  = (float*)(ws + o_dvec);
  float*  SS_T  = (float*)(ws + o_SS);
  float2* st1   = (float2*)(ws + o_st1);
  float2* st2   = (float2*)(ws + o_st2);
  float2* part  = (float2*)(ws + o_part);

  // zero only the halo borders (interiors fully overwritten)
  halo_zero_kernel<128><<<(32 * 260 * 16 + 255) / 256, 256, 0, stream>>>(act1p);
  halo_zero_kernel<256><<<(32 * 260 * 32 + 255) / 256, 256, 0, stream>>>(act2p);

  repack_w_kernel<<<1152, 256, 0, stream>>>(conv1_w, w1T, 128, 1152, 256 * 1152, 9, 3);
  repack_w_kernel<<<2304, 256, 0, stream>>>(mod_w, wmT, 256, 2304, 256 * 2304, 9, 3);
  repack_w_kernel<<<128, 256, 0, stream>>>(sc_w, scT, 128, 128, 256 * 128, 1, 1);
  modw_ss_kernel<<<256, 256, 0, stream>>>(mod_w, SS_T);
  temb_proj_kernel<<<32, 256, 0, stream>>>(temb, temb_w, temb_b, conv1_b, tb2);
  style_mvec_kernel<<<32, 256, 0, stream>>>(style, style_w, style_b, mvec);
  demod_kernel<<<32, 256, 0, stream>>>(mvec, SS_T, dvec);
  gn1_stats_kernel<<<1024, 256, 0, stream>>>(x, st1);
  gn1_apply_kernel<<<2048, 256, 0, stream>>>(x, st1, gn1_g, gn1_b, act1p, xh);

  igemm_kernel<0><<<dim3(1024, 2), 256, 0, stream>>>(act1p, w1T, tb2, nullptr, nullptr,
                                                     nullptr, h1, nullptr);

  gn2_part_kernel<<<512, 256, 0, stream>>>(h1, part);
  gn2_final_kernel<<<4, 256, 0, stream>>>(part, st2);
  gn2_apply_kernel<<<16384, 256, 0, stream>>>(h1, st2, gn2_g, gn2_b, mvec, act2p);

  igemm_kernel<2><<<dim3(1024, 2), 256, 0, stream>>>(act2p, wmT, dvec, xh, scT,
                                                     sc_b, nullptr, out);
}

// Round 4
// 420.071 us; speedup vs baseline: 1.2700x; 1.2005x over previous
//
#include <hip/hip_runtime.h>
#include <cstdint>

typedef unsigned short u16;
typedef unsigned int   u32;

typedef __attribute__((ext_vector_type(8))) short bf16x8;
typedef __attribute__((ext_vector_type(4))) float f32x4;

#define DEV __device__ __forceinline__

static constexpr int HP = 66, WP = 66;   // padded spatial

DEV u16 f2bf(float f) {
  u32 u = __float_as_uint(f);
  u32 r = (u + 0x7fffu + ((u >> 16) & 1u)) >> 16;
  return (u16)r;
}
DEV float bf2f(u16 v) { return __uint_as_float((u32)v << 16); }

DEV void gload_lds16(const void* g, void* s) {
  __builtin_amdgcn_global_load_lds(
      (const __attribute__((address_space(1))) void*)g,
      (__attribute__((address_space(3))) void*)s, 16, 0, 0);
}

// ---------------- weight repack: OIHW fp32 -> [co][(ky*3+kx)*Cin+ci] bf16 ----------
__global__ __launch_bounds__(256) void repack_w_kernel(const float* __restrict__ src,
                                                       u16* __restrict__ dst,
                                                       int Cin, int K, int total,
                                                       int ksq, int kdim) {
  for (int idx = blockIdx.x * 256 + threadIdx.x; idx < total; idx += gridDim.x * 256) {
    int co = idx / K;
    int r  = idx - co * K;
    int s  = r / Cin;
    int ci = r - s * Cin;
    int ky = s / kdim, kx = s - ky * kdim;
    dst[idx] = f2bf(src[(co * Cin + ci) * ksq + ky * kdim + kx]);
  }
}

// ---------------- SS_T[i][o] = sum_{kh,kw} mod_w[o][i]^2 ----------------
__global__ __launch_bounds__(256) void modw_ss_kernel(const float* __restrict__ w,
                                                      float* __restrict__ SS_T) {
  int o = blockIdx.x, i = threadIdx.x;
  const float* p = w + (size_t)(o * 256 + i) * 9;
  float s = 0.f;
#pragma unroll
  for (int k = 0; k < 9; ++k) s += p[k] * p[k];
  SS_T[i * 256 + o] = s;
}

// ---------------- mvec[b][i] = style . style_w[i] + style_b[i] + 1 ----------------
__global__ __launch_bounds__(256) void style_mvec_kernel(const float* __restrict__ style,
                                                         const float* __restrict__ style_w,
                                                         const float* __restrict__ style_b,
                                                         float* __restrict__ mvec) {
  __shared__ float st[512];
  int b = blockIdx.x, t = threadIdx.x;
  for (int k = t; k < 512; k += 256) st[k] = style[b * 512 + k];
  __syncthreads();
  const float4* wr = (const float4*)(style_w + t * 512);
  float acc = 0.f;
  for (int k = 0; k < 128; ++k) {
    float4 w4 = wr[k];
    acc += w4.x * st[k*4] + w4.y * st[k*4+1] + w4.z * st[k*4+2] + w4.w * st[k*4+3];
  }
  mvec[b * 256 + t] = acc + style_b[t] + 1.f;
}

// ---------------- dvec[b][o] = rsqrt(sum_i mvec[b][i]^2 * SS_T[i][o] + eps) ---------
__global__ __launch_bounds__(256) void demod_kernel(const float* __restrict__ mvec,
                                                    const float* __restrict__ SS_T,
                                                    float* __restrict__ dvec) {
  __shared__ float m2[256];
  int b = blockIdx.x, t = threadIdx.x;
  float mv = mvec[b * 256 + t];
  m2[t] = mv * mv;
  __syncthreads();
  float acc = 0.f;
  for (int i = 0; i < 256; ++i) acc += m2[i] * SS_T[i * 256 + t];
  dvec[b * 256 + t] = rsqrtf(acc + 1e-8f);
}

// ---------------- scTb[b][co][ci] = sc_w[co][ci] / dvec[b][co]  (bf16) --------------
__global__ __launch_bounds__(256) void scale_sc_kernel(const float* __restrict__ sc_w,
                                                       const float* __restrict__ dvec,
                                                       u16* __restrict__ scTb) {
  int idx = blockIdx.x * 256 + threadIdx.x;   // 32*256*128 total
  int ci = idx & 127;
  int co = (idx >> 7) & 255;
  int b  = idx >> 15;
  scTb[idx] = f2bf(sc_w[co * 128 + ci] / dvec[b * 256 + co]);
}

// ---------------- tb2[b][co] = swish(temb[b]) . temb_w[co] + temb_b + conv1_b -------
__global__ __launch_bounds__(256) void temb_proj_kernel(const float* __restrict__ temb,
                                                        const float* __restrict__ temb_w,
                                                        const float* __restrict__ temb_b,
                                                        const float* __restrict__ conv1_b,
                                                        float* __restrict__ tb2) {
  __shared__ float sw[512];
  int b = blockIdx.x, t = threadIdx.x;
  for (int k = t; k < 512; k += 256) {
    float v = temb[b * 512 + k];
    sw[k] = v / (1.f + __expf(-v));
  }
  __syncthreads();
  const float4* wr = (const float4*)(temb_w + t * 512);
  float acc = 0.f;
  for (int k = 0; k < 128; ++k) {
    float4 w4 = wr[k];
    acc += w4.x * sw[k*4] + w4.y * sw[k*4+1] + w4.z * sw[k*4+2] + w4.w * sw[k*4+3];
  }
  tb2[b * 256 + t] = acc + temb_b[t] + conv1_b[t];
}

// ---------------- halo zero: clear only border pixels of padded NHWC buffer ---------
template <int C>
__global__ __launch_bounds__(256) void halo_zero_kernel(u16* __restrict__ buf) {
  int idx = blockIdx.x * 256 + threadIdx.x;
  const int GR = C / 8;
  if (idx >= 32 * 260 * GR) return;
  int g = idx % GR;
  int p = (idx / GR) % 260;
  int b = idx / (GR * 260);
  int y, x;
  if (p < 66)       { y = 0;        x = p; }
  else if (p < 132) { y = 65;       x = p - 66; }
  else if (p < 196) { y = p - 131;  x = 0; }
  else              { y = p - 195;  x = 65; }
  uint4 z; z.x = 0; z.y = 0; z.z = 0; z.w = 0;
  *(uint4*)(buf + (((size_t)b * HP + y) * WP + x) * C + g * 8) = z;
}

// ---------------- GN1 stats ----------------
__global__ __launch_bounds__(256) void gn1_stats_kernel(const float* __restrict__ x,
                                                        float2* __restrict__ st1) {
  int bg = blockIdx.x;
  const float4* p = (const float4*)(x + (size_t)bg * 16384);
  float s = 0.f, s2 = 0.f;
  for (int i = threadIdx.x; i < 4096; i += 256) {
    float4 v = p[i];
    s  += v.x + v.y + v.z + v.w;
    s2 += v.x*v.x + v.y*v.y + v.z*v.z + v.w*v.w;
  }
  for (int d = 32; d; d >>= 1) { s += __shfl_down(s, d); s2 += __shfl_down(s2, d); }
  __shared__ float red[2][4];
  if ((threadIdx.x & 63) == 0) { red[0][threadIdx.x >> 6] = s; red[1][threadIdx.x >> 6] = s2; }
  __syncthreads();
  if (threadIdx.x == 0) {
    s  = red[0][0] + red[0][1] + red[0][2] + red[0][3];
    s2 = red[1][0] + red[1][1] + red[1][2] + red[1][3];
    float mean = s / 16384.f;
    float var  = s2 / 16384.f - mean * mean;
    st1[bg] = make_float2(mean, rsqrtf(var + 1e-5f));
  }
}

// ---------------- GN1 apply + swish -> act1p (padded NHWC bf16); also x -> xh NHWC --
__global__ __launch_bounds__(256) void gn1_apply_kernel(const float* __restrict__ x,
                                                        const float2* __restrict__ st1,
                                                        const float* __restrict__ g1,
                                                        const float* __restrict__ b1,
                                                        u16* __restrict__ act1p,
                                                        u16* __restrict__ xh) {
  __shared__ float xs[128][65];
  int blk = blockIdx.x;
  int b = blk >> 6, y = blk & 63;
  int t = threadIdx.x;
#pragma unroll 8
  for (int pass = 0; pass < 32; ++pass) {
    int c = pass * 4 + (t >> 6);
    xs[c][t & 63] = x[(((size_t)b * 128 + c) * 64 + y) * 64 + (t & 63)];
  }
  __syncthreads();
  for (int pass = 0; pass < 32; ++pass) {
    int xc = pass * 2 + (t >> 7);
    int c  = t & 127;
    float v = xs[c][xc];
    float2 ms = st1[b * 32 + (c >> 2)];
    float vn = (v - ms.x) * ms.y * g1[c] + b1[c];
    float sw = vn / (1.f + __expf(-vn));
    act1p[(((size_t)b * HP + (y + 1)) * WP + (xc + 1)) * 128 + c] = f2bf(sw);
    xh[(((size_t)b * 64 + y) * 64 + xc) * 128 + c] = f2bf(v);
  }
}

// ---------------- GN2 partial sums (h1 NHWC bf16) ----------------
__global__ __launch_bounds__(256) void gn2_part_kernel(const u16* __restrict__ h1,
                                                       float2* __restrict__ part) {
  int b = blockIdx.x >> 4, chunk = blockIdx.x & 15;
  int t = threadIdx.x;
  int g = t & 31, sub = t >> 5;
  float s = 0.f, s2 = 0.f;
  const u16* base = h1 + ((size_t)b * 4096 + chunk * 256) * 256 + g * 8;
  for (int pp = 0; pp < 32; ++pp) {
    uint4 raw = *(const uint4*)(base + (size_t)(pp * 8 + sub) * 256);
    const u16* rs = (const u16*)&raw;
#pragma unroll
    for (int e = 0; e < 8; ++e) { float v = bf2f(rs[e]); s += v; s2 += v * v; }
  }
  s += __shfl_xor(s, 32); s2 += __shfl_xor(s2, 32);
  __shared__ float red[2][4][32];
  int wv = t >> 6, ln = t & 63;
  if (ln < 32) { red[0][wv][ln] = s; red[1][wv][ln] = s2; }
  __syncthreads();
  if (t < 32) {
    float ts  = red[0][0][t] + red[0][1][t] + red[0][2][t] + red[0][3][t];
    float ts2 = red[1][0][t] + red[1][1][t] + red[1][2][t] + red[1][3][t];
    part[(b * 16 + chunk) * 32 + t] = make_float2(ts, ts2);
  }
}

__global__ void gn2_final_kernel(const float2* __restrict__ part, float2* __restrict__ st2) {
  int idx = blockIdx.x * 256 + threadIdx.x;
  if (idx >= 1024) return;
  int b = idx >> 5, g = idx & 31;
  float s = 0.f, s2 = 0.f;
  for (int c = 0; c < 16; ++c) { float2 p = part[(b * 16 + c) * 32 + g]; s += p.x; s2 += p.y; }
  float mean = s / 32768.f;
  float var  = s2 / 32768.f - mean * mean;
  st2[idx] = make_float2(mean, rsqrtf(var + 1e-5f));
}

// ------- GN2 apply + swish + input-channel modulation: h1 -> act2p (padded NHWC) ----
__global__ __launch_bounds__(256) void gn2_apply_kernel(const u16* __restrict__ h1,
                                                        const float2* __restrict__ st2,
                                                        const float* __restrict__ g2,
                                                        const float* __restrict__ b2,
                                                        const float* __restrict__ mvec,
                                                        u16* __restrict__ act2p) {
  int idx = blockIdx.x * 256 + threadIdx.x;  // granule id
  int gpix = idx >> 5;
  int gi = idx & 31;
  int c0 = gi * 8;
  int b = gpix >> 12, y = (gpix >> 6) & 63, x = gpix & 63;
  uint4 raw = *(const uint4*)(h1 + (size_t)gpix * 256 + c0);
  const u16* rs = (const u16*)&raw;
  float2 ms = st2[b * 32 + gi];
  const float* mv = mvec + b * 256 + c0;
  u16 outp[8];
#pragma unroll
  for (int e = 0; e < 8; ++e) {
    float v  = bf2f(rs[e]);
    float vn = (v - ms.x) * ms.y * g2[c0 + e] + b2[c0 + e];
    float sw = vn / (1.f + __expf(-vn));
    outp[e] = f2bf(sw * mv[e]);
  }
  *(uint4*)(act2p + (((size_t)b * HP + (y + 1)) * WP + (x + 1)) * 256 + c0) = *(const uint4*)outp;
}

// ---------- implicit-GEMM conv: 256x256 tile, 8 waves, BK=64, depth-2 pipeline ------
// MODE 0: conv1  (Cin=128, 3x3) -> h1 bf16 NHWC, epi = tb2 (incl conv1_b)
// MODE 2: modconv(Cin=256, 3x3) + fused 1x1 shortcut (weights pre-divided by dvec)
//         -> d_out NCHW fp32 = acc*dvec + sc_b
template <int MODE>
__global__ __launch_bounds__(512, 2) void igemm_kernel(const u16* __restrict__ act,
                                                       const u16* __restrict__ wT,
                                                       const float* __restrict__ epi,
                                                       const u16* __restrict__ xh,
                                                       const u16* __restrict__ scTb,
                                                       const float* __restrict__ sc_b,
                                                       u16* __restrict__ h1out,
                                                       float* __restrict__ fout) {
  constexpr int CIN    = (MODE == 0) ? 128 : 256;
  constexpr int NSUB   = CIN / 64;
  constexpr int KW     = CIN * 9;
  constexpr int NKMAIN = KW / 64;                 // 18 / 36
  constexpr int NKT    = (MODE == 2) ? NKMAIN + 2 : NKMAIN;

  __shared__ __align__(16) unsigned char lds[131072];
  const int tid  = threadIdx.x;
  const int wave = tid >> 6, lane = tid & 63;
  const int wm = wave >> 2, wn = wave & 3;        // 2 x 4 waves
  const int m_base = blockIdx.x * 256;
  const int bimg = m_base >> 12;

  const int grow  = tid >> 3;                     // 0..63
  const int gphys = tid & 7;
  const int glog  = gphys ^ (grow & 7);           // pre-swizzled source granule

  u32 pixA[4], rowB[4], pixX[4], rowS[4];
#pragma unroll
  for (int j = 0; j < 4; ++j) {
    int row = j * 64 + grow;
    int m = m_base + row;
    int y = (m >> 6) & 63, x = m & 63;
    pixA[j] = (u32)((bimg * HP + y) * WP + x) * CIN + glog * 8;
    rowB[j] = (u32)row * KW + glog * 8;
    if (MODE == 2) {
      pixX[j] = (u32)m * 128 + glog * 8;                     // xh flat [m][128]
      rowS[j] = (u32)(bimg * 256 + row) * 128 + glog * 8;    // scTb [b][co][128]
    }
  }

  f32x4 acc[8][4];
#pragma unroll
  for (int i = 0; i < 8; ++i)
#pragma unroll
    for (int j = 0; j < 4; ++j) acc[i][j] = (f32x4){0.f, 0.f, 0.f, 0.f};

  auto stage = [&](int kt, int buf) {
    unsigned char* As = lds + buf * 65536;
    unsigned char* Bs = As + 32768;
    if (MODE == 2 && kt >= NKMAIN) {
      u32 koff = (u32)(kt - NKMAIN) * 64;
#pragma unroll
      for (int j = 0; j < 4; ++j) {
        gload_lds16(xh   + pixX[j] + koff, As + j * 8192 + wave * 1024);
        gload_lds16(scTb + rowS[j] + koff, Bs + j * 8192 + wave * 1024);
      }
    } else {
      int tap = kt / NSUB;
      int kin = (kt % NSUB) * 64;
      int ky = tap / 3, kx = tap - ky * 3;
      u32 ka = (u32)((ky * WP + kx) * CIN + kin);
      u32 kb = (u32)kt * 64;
#pragma unroll
      for (int j = 0; j < 4; ++j) {
        gload_lds16(act + pixA[j] + ka, As + j * 8192 + wave * 1024);
        gload_lds16(wT  + rowB[j] + kb, Bs + j * 8192 + wave * 1024);
      }
    }
  };

  auto compute = [&](int buf) {
    unsigned char* As = lds + buf * 65536;
    unsigned char* Bs = As + 32768;
#pragma unroll
    for (int kk = 0; kk < 2; ++kk) {
      bf16x8 afr[8], bfr[4];
#pragma unroll
      for (int f = 0; f < 8; ++f) {
        int rowA = wm * 128 + f * 16 + (lane & 15);
        int gA = (kk * 4 + (lane >> 4)) ^ (rowA & 7);
        afr[f] = *(const bf16x8*)(As + rowA * 128 + gA * 16);
      }
#pragma unroll
      for (int f = 0; f < 4; ++f) {
        int rowBf = wn * 64 + f * 16 + (lane & 15);
        int gB = (kk * 4 + (lane >> 4)) ^ (rowBf & 7);
        bfr[f] = *(const bf16x8*)(Bs + rowBf * 128 + gB * 16);
      }
      __builtin_amdgcn_s_setprio(1);
#pragma unroll
      for (int fm = 0; fm < 8; ++fm)
#pragma unroll
        for (int fn = 0; fn < 4; ++fn)
          acc[fm][fn] = __builtin_amdgcn_mfma_f32_16x16x32_bf16(afr[fm], bfr[fn],
                                                                acc[fm][fn], 0, 0, 0);
      __builtin_amdgcn_s_setprio(0);
    }
  };

  // ---- depth-2 pipelined K-loop: counted vmcnt, never drained mid-loop ----
  stage(0, 0);
  stage(1, 1);
#pragma unroll 2
  for (int kt = 0; kt < NKT; ++kt) {
    const int cur = kt & 1;
    if (kt + 1 < NKT) { asm volatile("s_waitcnt vmcnt(8)" ::: "memory"); }
    else              { asm volatile("s_waitcnt vmcnt(0)" ::: "memory"); }
    __builtin_amdgcn_s_barrier();           // buf[cur] ready for all waves
    __builtin_amdgcn_sched_barrier(0);      // pin ds_reads below barrier
    compute(cur);
    asm volatile("s_waitcnt lgkmcnt(0)" ::: "memory");
    __builtin_amdgcn_s_barrier();           // all waves done reading buf[cur]
    __builtin_amdgcn_sched_barrier(0);      // pin stage below barrier
    if (kt + 2 < NKT) stage(kt + 2, cur);
  }

  if (MODE == 0) {
    const float* tbrow = epi + bimg * 256;
#pragma unroll
    for (int fm = 0; fm < 8; ++fm)
#pragma unroll
      for (int fn = 0; fn < 4; ++fn) {
        int co = wn * 64 + fn * 16 + (lane & 15);
        float add = tbrow[co];
#pragma unroll
        for (int i = 0; i < 4; ++i) {
          int m = m_base + wm * 128 + fm * 16 + ((lane >> 4) << 2) + i;
          h1out[(size_t)m * 256 + co] = f2bf(acc[fm][fn][i] + add);
        }
      }
  } else {
    float* tile = (float*)lds;              // [64][257] f32
    const int pixb = m_base & 4095;
#pragma unroll
    for (int c = 0; c < 4; ++c) {
      __syncthreads();
      if (wn == c) {
#pragma unroll
        for (int fn = 0; fn < 4; ++fn) {
          int nl = fn * 16 + (lane & 15);
          int co = c * 64 + nl;
          float dsc = epi[bimg * 256 + co];
          float scb = sc_b[co];
#pragma unroll
          for (int fm = 0; fm < 8; ++fm)
#pragma unroll
            for (int i = 0; i < 4; ++i) {
              int ml = wm * 128 + fm * 16 + ((lane >> 4) << 2) + i;
              tile[nl * 257 + ml] = acc[fm][fn][i] * dsc + scb;
            }
        }
      }
      __syncthreads();
#pragma unroll 4
      for (int it = 0; it < 32; ++it) {
        int lin = it * 512 + tid;
        int co_l = lin >> 8, ml = lin & 255;
        fout[((size_t)(bimg * 256 + c * 64 + co_l)) * 4096 + pixb + ml] =
            tile[co_l * 257 + ml];
      }
    }
  }
}

// ------------------------------- launch -------------------------------
extern "C" void kernel_launch(void* const* d_in, const int* in_sizes, int n_in,
                              void* d_out, int out_size, void* d_ws, size_t ws_size,
                              hipStream_t stream) {
  const float* x       = (const float*)d_in[0];
  const float* temb    = (const float*)d_in[1];
  const float* style   = (const float*)d_in[2];
  const float* gn1_g   = (const float*)d_in[3];
  const float* gn1_b   = (const float*)d_in[4];
  const float* conv1_w = (const float*)d_in[5];
  const float* conv1_b = (const float*)d_in[6];
  const float* temb_w  = (const float*)d_in[7];
  const float* temb_b  = (const float*)d_in[8];
  const float* gn2_g   = (const float*)d_in[9];
  const float* gn2_b   = (const float*)d_in[10];
  const float* style_w = (const float*)d_in[11];
  const float* style_b = (const float*)d_in[12];
  const float* mod_w   = (const float*)d_in[13];
  const float* sc_w    = (const float*)d_in[14];
  const float* sc_b    = (const float*)d_in[15];
  float* out = (float*)d_out;
  char* ws = (char*)d_ws;

  size_t o = 0;
  auto alloc = [&](size_t bytes) { size_t r = o; o += (bytes + 255) & ~(size_t)255; return r; };
  const size_t act1p_bytes = (size_t)32 * HP * WP * 128 * 2;
  const size_t xh_bytes    = (size_t)32 * 64 * 64 * 128 * 2;
  const size_t h1_bytes    = (size_t)32 * 4096 * 256 * 2;
  const size_t act2p_bytes = (size_t)32 * HP * WP * 256 * 2;
  size_t o_act1p = alloc(act1p_bytes);
  size_t o_xh    = alloc(xh_bytes);
  size_t o_h1    = alloc(h1_bytes);
  size_t o_act2p = alloc(act2p_bytes);
  size_t o_w1T   = alloc((size_t)256 * 1152 * 2);
  size_t o_wmT   = alloc((size_t)256 * 2304 * 2);
  size_t o_scTb  = alloc((size_t)32 * 256 * 128 * 2);
  size_t o_tb2   = alloc(8192 * 4);
  size_t o_mvec  = alloc(8192 * 4);
  size_t o_dvec  = alloc(8192 * 4);
  size_t o_SS    = alloc((size_t)256 * 256 * 4);
  size_t o_st1   = alloc(1024 * 8);
  size_t o_st2   = alloc(1024 * 8);
  size_t o_part  = alloc(512 * 32 * 8);
  if (ws_size < o) return;

  u16*    act1p = (u16*)(ws + o_act1p);
  u16*    xh    = (u16*)(ws + o_xh);
  u16*    h1    = (u16*)(ws + o_h1);
  u16*    act2p = (u16*)(ws + o_act2p);
  u16*    w1T   = (u16*)(ws + o_w1T);
  u16*    wmT   = (u16*)(ws + o_wmT);
  u16*    scTb  = (u16*)(ws + o_scTb);
  float*  tb2   = (float*)(ws + o_tb2);
  float*  mvec  = (float*)(ws + o_mvec);
  float*  dvec  = (float*)(ws + o_dvec);
  float*  SS_T  = (float*)(ws + o_SS);
  float2* st1   = (float2*)(ws + o_st1);
  float2* st2   = (float2*)(ws + o_st2);
  float2* part  = (float2*)(ws + o_part);

  // zero only the halo borders (interiors fully overwritten)
  halo_zero_kernel<128><<<(32 * 260 * 16 + 255) / 256, 256, 0, stream>>>(act1p);
  halo_zero_kernel<256><<<(32 * 260 * 32 + 255) / 256, 256, 0, stream>>>(act2p);

  repack_w_kernel<<<1152, 256, 0, stream>>>(conv1_w, w1T, 128, 1152, 256 * 1152, 9, 3);
  repack_w_kernel<<<2304, 256, 0, stream>>>(mod_w, wmT, 256, 2304, 256 * 2304, 9, 3);
  modw_ss_kernel<<<256, 256, 0, stream>>>(mod_w, SS_T);
  temb_proj_kernel<<<32, 256, 0, stream>>>(temb, temb_w, temb_b, conv1_b, tb2);
  style_mvec_kernel<<<32, 256, 0, stream>>>(style, style_w, style_b, mvec);
  demod_kernel<<<32, 256, 0, stream>>>(mvec, SS_T, dvec);
  scale_sc_kernel<<<4096, 256, 0, stream>>>(sc_w, dvec, scTb);
  gn1_stats_kernel<<<1024, 256, 0, stream>>>(x, st1);
  gn1_apply_kernel<<<2048, 256, 0, stream>>>(x, st1, gn1_g, gn1_b, act1p, xh);

  igemm_kernel<0><<<512, 512, 0, stream>>>(act1p, w1T, tb2, nullptr, nullptr,
                                           nullptr, h1, nullptr);

  gn2_part_kernel<<<512, 256, 0, stream>>>(h1, part);
  gn2_final_kernel<<<4, 256, 0, stream>>>(part, st2);
  gn2_apply_kernel<<<16384, 256, 0, stream>>>(h1, st2, gn2_g, gn2_b, mvec, act2p);

  igemm_kernel<2><<<512, 512, 0, stream>>>(act2p, wmT, dvec, xh, scTb,
                                           sc_b, nullptr, out);
}

// Round 5
// 373.460 us; speedup vs baseline: 1.4285x; 1.1248x over previous
//
#include <hip/hip_runtime.h>
#include <cstdint>

typedef unsigned short u16;
typedef unsigned int   u32;

typedef __attribute__((ext_vector_type(8))) short bf16x8;
typedef __attribute__((ext_vector_type(4))) float f32x4;

#define DEV __device__ __forceinline__

static constexpr int HP = 66, WP = 66;   // padded spatial

DEV u16 f2bf(float f) {
  u32 u = __float_as_uint(f);
  u32 r = (u + 0x7fffu + ((u >> 16) & 1u)) >> 16;
  return (u16)r;
}
DEV float bf2f(u16 v) { return __uint_as_float((u32)v << 16); }

DEV void gload_lds16(const void* g, void* s) {
  __builtin_amdgcn_global_load_lds(
      (const __attribute__((address_space(1))) void*)g,
      (__attribute__((address_space(3))) void*)s, 16, 0, 0);
}

// ---------------- weight repack: OIHW fp32 -> [co][(ky*3+kx)*Cin+ci] bf16 ----------
__global__ __launch_bounds__(256) void repack_w_kernel(const float* __restrict__ src,
                                                       u16* __restrict__ dst,
                                                       int Cin, int K, int total,
                                                       int ksq, int kdim) {
  for (int idx = blockIdx.x * 256 + threadIdx.x; idx < total; idx += gridDim.x * 256) {
    int co = idx / K;
    int r  = idx - co * K;
    int s  = r / Cin;
    int ci = r - s * Cin;
    int ky = s / kdim, kx = s - ky * kdim;
    dst[idx] = f2bf(src[(co * Cin + ci) * ksq + ky * kdim + kx]);
  }
}

// ---------------- SS_T[i][o] = sum_{kh,kw} mod_w[o][i]^2 ----------------
__global__ __launch_bounds__(256) void modw_ss_kernel(const float* __restrict__ w,
                                                      float* __restrict__ SS_T) {
  int o = blockIdx.x, i = threadIdx.x;
  const float* p = w + (size_t)(o * 256 + i) * 9;
  float s = 0.f;
#pragma unroll
  for (int k = 0; k < 9; ++k) s += p[k] * p[k];
  SS_T[i * 256 + o] = s;
}

// ---------------- mvec[b][i] = style . style_w[i] + style_b[i] + 1 ----------------
__global__ __launch_bounds__(256) void style_mvec_kernel(const float* __restrict__ style,
                                                         const float* __restrict__ style_w,
                                                         const float* __restrict__ style_b,
                                                         float* __restrict__ mvec) {
  __shared__ float st[512];
  int b = blockIdx.x, t = threadIdx.x;
  for (int k = t; k < 512; k += 256) st[k] = style[b * 512 + k];
  __syncthreads();
  const float4* wr = (const float4*)(style_w + t * 512);
  float acc = 0.f;
  for (int k = 0; k < 128; ++k) {
    float4 w4 = wr[k];
    acc += w4.x * st[k*4] + w4.y * st[k*4+1] + w4.z * st[k*4+2] + w4.w * st[k*4+3];
  }
  mvec[b * 256 + t] = acc + style_b[t] + 1.f;
}

// ---------------- dvec[b][o] = rsqrt(sum_i mvec[b][i]^2 * SS_T[i][o] + eps) ---------
__global__ __launch_bounds__(256) void demod_kernel(const float* __restrict__ mvec,
                                                    const float* __restrict__ SS_T,
                                                    float* __restrict__ dvec) {
  __shared__ float m2[256];
  int b = blockIdx.x, t = threadIdx.x;
  float mv = mvec[b * 256 + t];
  m2[t] = mv * mv;
  __syncthreads();
  float acc = 0.f;
  for (int i = 0; i < 256; ++i) acc += m2[i] * SS_T[i * 256 + t];
  dvec[b * 256 + t] = rsqrtf(acc + 1e-8f);
}

// ---------------- scTb[b][co][ci] = sc_w[co][ci] / dvec[b][co]  (bf16) --------------
__global__ __launch_bounds__(256) void scale_sc_kernel(const float* __restrict__ sc_w,
                                                       const float* __restrict__ dvec,
                                                       u16* __restrict__ scTb) {
  int idx = blockIdx.x * 256 + threadIdx.x;   // 32*256*128 total
  int ci = idx & 127;
  int co = (idx >> 7) & 255;
  int b  = idx >> 15;
  scTb[idx] = f2bf(sc_w[co * 128 + ci] / dvec[b * 256 + co]);
}

// ---------------- tb2[b][co] = swish(temb[b]) . temb_w[co] + temb_b + conv1_b -------
__global__ __launch_bounds__(256) void temb_proj_kernel(const float* __restrict__ temb,
                                                        const float* __restrict__ temb_w,
                                                        const float* __restrict__ temb_b,
                                                        const float* __restrict__ conv1_b,
                                                        float* __restrict__ tb2) {
  __shared__ float sw[512];
  int b = blockIdx.x, t = threadIdx.x;
  for (int k = t; k < 512; k += 256) {
    float v = temb[b * 512 + k];
    sw[k] = v / (1.f + __expf(-v));
  }
  __syncthreads();
  const float4* wr = (const float4*)(temb_w + t * 512);
  float acc = 0.f;
  for (int k = 0; k < 128; ++k) {
    float4 w4 = wr[k];
    acc += w4.x * sw[k*4] + w4.y * sw[k*4+1] + w4.z * sw[k*4+2] + w4.w * sw[k*4+3];
  }
  tb2[b * 256 + t] = acc + temb_b[t] + conv1_b[t];
}

// ---------------- halo zero: clear only border pixels of padded NHWC buffer ---------
template <int C>
__global__ __launch_bounds__(256) void halo_zero_kernel(u16* __restrict__ buf) {
  int idx = blockIdx.x * 256 + threadIdx.x;
  const int GR = C / 8;
  if (idx >= 32 * 260 * GR) return;
  int g = idx % GR;
  int p = (idx / GR) % 260;
  int b = idx / (GR * 260);
  int y, x;
  if (p < 66)       { y = 0;        x = p; }
  else if (p < 132) { y = 65;       x = p - 66; }
  else if (p < 196) { y = p - 131;  x = 0; }
  else              { y = p - 195;  x = 65; }
  uint4 z; z.x = 0; z.y = 0; z.z = 0; z.w = 0;
  *(uint4*)(buf + (((size_t)b * HP + y) * WP + x) * C + g * 8) = z;
}

// ---------------- GN1 stats ----------------
__global__ __launch_bounds__(256) void gn1_stats_kernel(const float* __restrict__ x,
                                                        float2* __restrict__ st1) {
  int bg = blockIdx.x;
  const float4* p = (const float4*)(x + (size_t)bg * 16384);
  float s = 0.f, s2 = 0.f;
  for (int i = threadIdx.x; i < 4096; i += 256) {
    float4 v = p[i];
    s  += v.x + v.y + v.z + v.w;
    s2 += v.x*v.x + v.y*v.y + v.z*v.z + v.w*v.w;
  }
  for (int d = 32; d; d >>= 1) { s += __shfl_down(s, d); s2 += __shfl_down(s2, d); }
  __shared__ float red[2][4];
  if ((threadIdx.x & 63) == 0) { red[0][threadIdx.x >> 6] = s; red[1][threadIdx.x >> 6] = s2; }
  __syncthreads();
  if (threadIdx.x == 0) {
    s  = red[0][0] + red[0][1] + red[0][2] + red[0][3];
    s2 = red[1][0] + red[1][1] + red[1][2] + red[1][3];
    float mean = s / 16384.f;
    float var  = s2 / 16384.f - mean * mean;
    st1[bg] = make_float2(mean, rsqrtf(var + 1e-5f));
  }
}

// ---------------- GN1 apply + swish -> act1p (padded NHWC bf16); also x -> xh NHWC --
__global__ __launch_bounds__(256) void gn1_apply_kernel(const float* __restrict__ x,
                                                        const float2* __restrict__ st1,
                                                        const float* __restrict__ g1,
                                                        const float* __restrict__ b1,
                                                        u16* __restrict__ act1p,
                                                        u16* __restrict__ xh) {
  __shared__ float xs[128][65];
  int blk = blockIdx.x;
  int b = blk >> 6, y = blk & 63;
  int t = threadIdx.x;
#pragma unroll 8
  for (int pass = 0; pass < 32; ++pass) {
    int c = pass * 4 + (t >> 6);
    xs[c][t & 63] = x[(((size_t)b * 128 + c) * 64 + y) * 64 + (t & 63)];
  }
  __syncthreads();
  for (int pass = 0; pass < 32; ++pass) {
    int xc = pass * 2 + (t >> 7);
    int c  = t & 127;
    float v = xs[c][xc];
    float2 ms = st1[b * 32 + (c >> 2)];
    float vn = (v - ms.x) * ms.y * g1[c] + b1[c];
    float sw = vn / (1.f + __expf(-vn));
    act1p[(((size_t)b * HP + (y + 1)) * WP + (xc + 1)) * 128 + c] = f2bf(sw);
    xh[(((size_t)b * 64 + y) * 64 + xc) * 128 + c] = f2bf(v);
  }
}

// ---------------- GN2 partial sums (h1 NHWC bf16) ----------------
__global__ __launch_bounds__(256) void gn2_part_kernel(const u16* __restrict__ h1,
                                                       float2* __restrict__ part) {
  int b = blockIdx.x >> 4, chunk = blockIdx.x & 15;
  int t = threadIdx.x;
  int g = t & 31, sub = t >> 5;
  float s = 0.f, s2 = 0.f;
  const u16* base = h1 + ((size_t)b * 4096 + chunk * 256) * 256 + g * 8;
  for (int pp = 0; pp < 32; ++pp) {
    uint4 raw = *(const uint4*)(base + (size_t)(pp * 8 + sub) * 256);
    const u16* rs = (const u16*)&raw;
#pragma unroll
    for (int e = 0; e < 8; ++e) { float v = bf2f(rs[e]); s += v; s2 += v * v; }
  }
  s += __shfl_xor(s, 32); s2 += __shfl_xor(s2, 32);
  __shared__ float red[2][4][32];
  int wv = t >> 6, ln = t & 63;
  if (ln < 32) { red[0][wv][ln] = s; red[1][wv][ln] = s2; }
  __syncthreads();
  if (t < 32) {
    float ts  = red[0][0][t] + red[0][1][t] + red[0][2][t] + red[0][3][t];
    float ts2 = red[1][0][t] + red[1][1][t] + red[1][2][t] + red[1][3][t];
    part[(b * 16 + chunk) * 32 + t] = make_float2(ts, ts2);
  }
}

__global__ void gn2_final_kernel(const float2* __restrict__ part, float2* __restrict__ st2) {
  int idx = blockIdx.x * 256 + threadIdx.x;
  if (idx >= 1024) return;
  int b = idx >> 5, g = idx & 31;
  float s = 0.f, s2 = 0.f;
  for (int c = 0; c < 16; ++c) { float2 p = part[(b * 16 + c) * 32 + g]; s += p.x; s2 += p.y; }
  float mean = s / 32768.f;
  float var  = s2 / 32768.f - mean * mean;
  st2[idx] = make_float2(mean, rsqrtf(var + 1e-5f));
}

// ------- GN2 apply + swish + input-channel modulation: h1 -> act2p (padded NHWC) ----
__global__ __launch_bounds__(256) void gn2_apply_kernel(const u16* __restrict__ h1,
                                                        const float2* __restrict__ st2,
                                                        const float* __restrict__ g2,
                                                        const float* __restrict__ b2,
                                                        const float* __restrict__ mvec,
                                                        u16* __restrict__ act2p) {
  int idx = blockIdx.x * 256 + threadIdx.x;  // granule id
  int gpix = idx >> 5;
  int gi = idx & 31;
  int c0 = gi * 8;
  int b = gpix >> 12, y = (gpix >> 6) & 63, x = gpix & 63;
  uint4 raw = *(const uint4*)(h1 + (size_t)gpix * 256 + c0);
  const u16* rs = (const u16*)&raw;
  float2 ms = st2[b * 32 + gi];
  const float* mv = mvec + b * 256 + c0;
  u16 outp[8];
#pragma unroll
  for (int e = 0; e < 8; ++e) {
    float v  = bf2f(rs[e]);
    float vn = (v - ms.x) * ms.y * g2[c0 + e] + b2[c0 + e];
    float sw = vn / (1.f + __expf(-vn));
    outp[e] = f2bf(sw * mv[e]);
  }
  *(uint4*)(act2p + (((size_t)b * HP + (y + 1)) * WP + (x + 1)) * 256 + c0) = *(const uint4*)outp;
}

// ---------- implicit-GEMM conv: 256x256 tile, 8 waves, BK=64, 4-phase schedule ------
// LDS row permutations (so each phase consumes a contiguous 16KB half-tile):
//   A: lds_row = swap bits6,7 of local m   (half h = fm-half)
//   B: lds_row = (co bit5)*128 + (co>>6)*32 + (co&31)   (half g = fn-half)
// Phases per K-tile: (h0,g0) (h0,g1) (h1,g1) (h1,g0); stage order Ah0,Bg0,Bg1,Ah1
// into the OTHER buffer; uniform vmcnt(6) = 3 half-tiles in flight.
template <int MODE>
__global__ __launch_bounds__(512, 2) void igemm_kernel(const u16* __restrict__ act,
                                                       const u16* __restrict__ wT,
                                                       const float* __restrict__ epi,
                                                       const u16* __restrict__ xh,
                                                       const u16* __restrict__ scTb,
                                                       const float* __restrict__ sc_b,
                                                       u16* __restrict__ h1out,
                                                       float* __restrict__ fout) {
  constexpr int CIN    = (MODE == 0) ? 128 : 256;
  constexpr int NSUB   = CIN / 64;
  constexpr int KW     = CIN * 9;
  constexpr int NKMAIN = KW / 64;                 // 18 / 36
  constexpr int NKT    = (MODE == 2) ? NKMAIN + 2 : NKMAIN;

  __shared__ __align__(16) unsigned char lds[131072];
  const int tid  = threadIdx.x;
  const int wave = tid >> 6, lane = tid & 63;
  const int wm = wave >> 2, wn = wave & 3;        // 2 x 4 waves
  const int m_base = blockIdx.x * 256;
  const int bimg = m_base >> 12;
  const int ln = lane & 15, l4 = lane >> 4;

  // staging lane constants
  const int srow = lane >> 3;                     // 0..7
  const int glog = (lane & 7) ^ srow;             // pre-swizzled source granule

  u32 pixA[2][2], pixX[2][2], rowB[2][2], rowS[2][2];
#pragma unroll
  for (int j = 0; j < 2; ++j)
#pragma unroll
    for (int h = 0; h < 2; ++h) {
      // A source: local m for lds half h, this wave's chunk, sub-chunk j
      int mlocal = (wave & 3) * 16 + j * 8 + srow + h * 64 + (wave >> 2) * 128;
      int m = m_base + mlocal;
      int y = (m >> 6) & 63, x = m & 63;
      pixA[j][h] = (u32)((bimg * HP + y) * WP + x) * CIN + glog * 8;
      if (MODE == 2) pixX[j][h] = (u32)m * 128 + glog * 8;
      // B source: co for lds half g(=h), this wave's chunk, sub-chunk j
      int co = (wave >> 1) * 64 + h * 32 + (wave & 1) * 16 + j * 8 + srow;
      rowB[j][h] = (u32)co * KW + glog * 8;
      if (MODE == 2) rowS[j][h] = (u32)(bimg * 256 + co) * 128 + glog * 8;
    }

  f32x4 acc[8][4];
#pragma unroll
  for (int i = 0; i < 8; ++i)
#pragma unroll
    for (int j = 0; j < 4; ++j) acc[i][j] = (f32x4){0.f, 0.f, 0.f, 0.f};

  auto stageA = [&](int kt, int h, int buf) {
    unsigned char* dst = lds + buf * 65536 + h * 16384 + wave * 2048;
    if (MODE == 2 && kt >= NKMAIN) {
      u32 ko = (u32)(kt - NKMAIN) * 64;
      gload_lds16(xh + pixX[0][h] + ko, dst);
      gload_lds16(xh + pixX[1][h] + ko, dst + 1024);
    } else {
      int tap = kt / NSUB;
      int kin = (kt - tap * NSUB) * 64;
      int ky = tap / 3, kx = tap - ky * 3;
      u32 ko = (u32)((ky * WP + kx) * CIN + kin);
      gload_lds16(act + pixA[0][h] + ko, dst);
      gload_lds16(act + pixA[1][h] + ko, dst + 1024);
    }
  };
  auto stageB = [&](int kt, int g, int buf) {
    unsigned char* dst = lds + buf * 65536 + 32768 + g * 16384 + wave * 2048;
    if (MODE == 2 && kt >= NKMAIN) {
      u32 ko = (u32)(kt - NKMAIN) * 64;
      gload_lds16(scTb + rowS[0][g] + ko, dst);
      gload_lds16(scTb + rowS[1][g] + ko, dst + 1024);
    } else {
      u32 ko = (u32)kt * 64;
      gload_lds16(wT + rowB[0][g] + ko, dst);
      gload_lds16(wT + rowB[1][g] + ko, dst + 1024);
    }
  };

  bf16x8 af[8], bf[4];
  auto ldA = [&](int h, int buf) {
    const unsigned char* As = lds + buf * 65536;
#pragma unroll
    for (int f = 0; f < 4; ++f)
#pragma unroll
      for (int kk = 0; kk < 2; ++kk) {
        int lr = h * 128 + wm * 64 + f * 16 + ln;
        int gr = (kk * 4 + l4) ^ (ln & 7);
        af[f * 2 + kk] = *(const bf16x8*)(As + lr * 128 + gr * 16);
      }
  };
  auto ldB = [&](int g, int buf) {
    const unsigned char* Bs = lds + buf * 65536 + 32768;
#pragma unroll
    for (int f1 = 0; f1 < 2; ++f1)
#pragma unroll
      for (int kk = 0; kk < 2; ++kk) {
        int lr = g * 128 + wn * 32 + f1 * 16 + ln;
        int gr = (kk * 4 + l4) ^ (ln & 7);
        bf[f1 * 2 + kk] = *(const bf16x8*)(Bs + lr * 128 + gr * 16);
      }
  };
  auto mmac = [&](int h, int g) {
    __builtin_amdgcn_s_setprio(1);
#pragma unroll
    for (int f = 0; f < 4; ++f)
#pragma unroll
      for (int f1 = 0; f1 < 2; ++f1)
#pragma unroll
        for (int kk = 0; kk < 2; ++kk)
          acc[h * 4 + f][g * 2 + f1] = __builtin_amdgcn_mfma_f32_16x16x32_bf16(
              af[f * 2 + kk], bf[f1 * 2 + kk], acc[h * 4 + f][g * 2 + f1], 0, 0, 0);
    __builtin_amdgcn_s_setprio(0);
  };

#define PHASE_BAR() do { __builtin_amdgcn_sched_barrier(0); \
    __builtin_amdgcn_s_barrier(); __builtin_amdgcn_sched_barrier(0); } while (0)

  // prologue: tile 0 -> buf0, in consumption order Ah0, Bg0, Bg1, Ah1
  stageA(0, 0, 0); stageB(0, 0, 0); stageB(0, 1, 0); stageA(0, 1, 0);

#pragma unroll 2
  for (int kt = 0; kt < NKT - 1; ++kt) {
    const int cur = kt & 1, nxt = cur ^ 1;
    // ph0: (h0,g0)
    stageA(kt + 1, 0, nxt);
    asm volatile("s_waitcnt vmcnt(6)" ::: "memory");
    PHASE_BAR();
    ldB(0, cur); ldA(0, cur);
    mmac(0, 0);
    // ph1: (h0,g1)
    stageB(kt + 1, 0, nxt);
    asm volatile("s_waitcnt vmcnt(6)" ::: "memory");
    PHASE_BAR();
    ldB(1, cur);
    mmac(0, 1);
    // ph2: (h1,g1)
    stageB(kt + 1, 1, nxt);
    asm volatile("s_waitcnt vmcnt(6)" ::: "memory");
    PHASE_BAR();
    ldA(1, cur);
    mmac(1, 1);
    // ph3: (h1,g0)
    stageA(kt + 1, 1, nxt);
    PHASE_BAR();
    ldB(0, cur);
    mmac(1, 0);
  }
  {  // last tile (no staging): drain progressively
    const int cur = (NKT - 1) & 1;
    asm volatile("s_waitcnt vmcnt(4)" ::: "memory");
    PHASE_BAR();
    ldB(0, cur); ldA(0, cur); mmac(0, 0);
    asm volatile("s_waitcnt vmcnt(2)" ::: "memory");
    PHASE_BAR();
    ldB(1, cur); mmac(0, 1);
    asm volatile("s_waitcnt vmcnt(0)" ::: "memory");
    PHASE_BAR();
    ldA(1, cur); mmac(1, 1);
    PHASE_BAR();
    ldB(0, cur); mmac(1, 0);
  }
#undef PHASE_BAR

  if (MODE == 0) {
    const float* tbrow = epi + bimg * 256;
#pragma unroll
    for (int fm = 0; fm < 8; ++fm)
#pragma unroll
      for (int fn = 0; fn < 4; ++fn) {
        int co = wn * 64 + fn * 16 + ln;
        float add = tbrow[co];
#pragma unroll
        for (int i = 0; i < 4; ++i) {
          int m = m_base + wm * 128 + fm * 16 + (l4 << 2) + i;
          h1out[(size_t)m * 256 + co] = f2bf(acc[fm][fn][i] + add);
        }
      }
  } else {
    float* tile = (float*)lds;              // [64][257] f32
    const int pixb = m_base & 4095;
#pragma unroll
    for (int c = 0; c < 4; ++c) {
      __syncthreads();
      if (wn == c) {
#pragma unroll
        for (int fn = 0; fn < 4; ++fn) {
          int nl = fn * 16 + ln;
          int co = c * 64 + nl;
          float dsc = epi[bimg * 256 + co];
          float scb = sc_b[co];
#pragma unroll
          for (int fm = 0; fm < 8; ++fm)
#pragma unroll
            for (int i = 0; i < 4; ++i) {
              int ml = wm * 128 + fm * 16 + (l4 << 2) + i;
              tile[nl * 257 + ml] = acc[fm][fn][i] * dsc + scb;
            }
        }
      }
      __syncthreads();
#pragma unroll 4
      for (int it = 0; it < 32; ++it) {
        int lin = it * 512 + tid;
        int co_l = lin >> 8, ml = lin & 255;
        fout[((size_t)(bimg * 256 + c * 64 + co_l)) * 4096 + pixb + ml] =
            tile[co_l * 257 + ml];
      }
    }
  }
}

// ------------------------------- launch -------------------------------
extern "C" void kernel_launch(void* const* d_in, const int* in_sizes, int n_in,
                              void* d_out, int out_size, void* d_ws, size_t ws_size,
                              hipStream_t stream) {
  const float* x       = (const float*)d_in[0];
  const float* temb    = (const float*)d_in[1];
  const float* style   = (const float*)d_in[2];
  const float* gn1_g   = (const float*)d_in[3];
  const float* gn1_b   = (const float*)d_in[4];
  const float* conv1_w = (const float*)d_in[5];
  const float* conv1_b = (const float*)d_in[6];
  const float* temb_w  = (const float*)d_in[7];
  const float* temb_b  = (const float*)d_in[8];
  const float* gn2_g   = (const float*)d_in[9];
  const float* gn2_b   = (const float*)d_in[10];
  const float* style_w = (const float*)d_in[11];
  const float* style_b = (const float*)d_in[12];
  const float* mod_w   = (const float*)d_in[13];
  const float* sc_w    = (const float*)d_in[14];
  const float* sc_b    = (const float*)d_in[15];
  float* out = (float*)d_out;
  char* ws = (char*)d_ws;

  size_t o = 0;
  auto alloc = [&](size_t bytes) { size_t r = o; o += (bytes + 255) & ~(size_t)255; return r; };
  const size_t act1p_bytes = (size_t)32 * HP * WP * 128 * 2;
  const size_t xh_bytes    = (size_t)32 * 64 * 64 * 128 * 2;
  const size_t h1_bytes    = (size_t)32 * 4096 * 256 * 2;
  const size_t act2p_bytes = (size_t)32 * HP * WP * 256 * 2;
  size_t o_act1p = alloc(act1p_bytes);
  size_t o_xh    = alloc(xh_bytes);
  size_t o_h1    = alloc(h1_bytes);
  size_t o_act2p = alloc(act2p_bytes);
  size_t o_w1T   = alloc((size_t)256 * 1152 * 2);
  size_t o_wmT   = alloc((size_t)256 * 2304 * 2);
  size_t o_scTb  = alloc((size_t)32 * 256 * 128 * 2);
  size_t o_tb2   = alloc(8192 * 4);
  size_t o_mvec  = alloc(8192 * 4);
  size_t o_dvec  = alloc(8192 * 4);
  size_t o_SS    = alloc((size_t)256 * 256 * 4);
  size_t o_st1   = alloc(1024 * 8);
  size_t o_st2   = alloc(1024 * 8);
  size_t o_part  = alloc(512 * 32 * 8);
  if (ws_size < o) return;

  u16*    act1p = (u16*)(ws + o_act1p);
  u16*    xh    = (u16*)(ws + o_xh);
  u16*    h1    = (u16*)(ws + o_h1);
  u16*    act2p = (u16*)(ws + o_act2p);
  u16*    w1T   = (u16*)(ws + o_w1T);
  u16*    wmT   = (u16*)(ws + o_wmT);
  u16*    scTb  = (u16*)(ws + o_scTb);
  float*  tb2   = (float*)(ws + o_tb2);
  float*  mvec  = (float*)(ws + o_mvec);
  float*  dvec  = (float*)(ws + o_dvec);
  float*  SS_T  = (float*)(ws + o_SS);
  float2* st1   = (float2*)(ws + o_st1);
  float2* st2   = (float2*)(ws + o_st2);
  float2* part  = (float2*)(ws + o_part);

  // zero only the halo borders (interiors fully overwritten)
  halo_zero_kernel<128><<<(32 * 260 * 16 + 255) / 256, 256, 0, stream>>>(act1p);
  halo_zero_kernel<256><<<(32 * 260 * 32 + 255) / 256, 256, 0, stream>>>(act2p);

  repack_w_kernel<<<1152, 256, 0, stream>>>(conv1_w, w1T, 128, 1152, 256 * 1152, 9, 3);
  repack_w_kernel<<<2304, 256, 0, stream>>>(mod_w, wmT, 256, 2304, 256 * 2304, 9, 3);
  modw_ss_kernel<<<256, 256, 0, stream>>>(mod_w, SS_T);
  temb_proj_kernel<<<32, 256, 0, stream>>>(temb, temb_w, temb_b, conv1_b, tb2);
  style_mvec_kernel<<<32, 256, 0, stream>>>(style, style_w, style_b, mvec);
  demod_kernel<<<32, 256, 0, stream>>>(mvec, SS_T, dvec);
  scale_sc_kernel<<<4096, 256, 0, stream>>>(sc_w, dvec, scTb);
  gn1_stats_kernel<<<1024, 256, 0, stream>>>(x, st1);
  gn1_apply_kernel<<<2048, 256, 0, stream>>>(x, st1, gn1_g, gn1_b, act1p, xh);

  igemm_kernel<0><<<512, 512, 0, stream>>>(act1p, w1T, tb2, nullptr, nullptr,
                                           nullptr, h1, nullptr);

  gn2_part_kernel<<<512, 256, 0, stream>>>(h1, part);
  gn2_final_kernel<<<4, 256, 0, stream>>>(part, st2);
  gn2_apply_kernel<<<16384, 256, 0, stream>>>(h1, st2, gn2_g, gn2_b, mvec, act2p);

  igemm_kernel<2><<<512, 512, 0, stream>>>(act2p, wmT, dvec, xh, scTb,
                                           sc_b, nullptr, out);
}